// Round 2
// baseline (204.119 us; speedup 1.0000x reference)
//
#include <hip/hip_runtime.h>
#include <math.h>

#define BB 32
#define TT 1024
#define JJ 128
#define DD 256

// ---------------------------------------------------------------------------
// K1: ch[b,t] = C[b,t,:]·w_h ; qu[b,j] = Q[b,j,:]·w_u   (one wave per row)
// ---------------------------------------------------------------------------
__global__ __launch_bounds__(256) void k_rowdots(const float* __restrict__ C,
                                                 const float* __restrict__ Q,
                                                 const float* __restrict__ w,
                                                 float* __restrict__ ch,
                                                 float* __restrict__ qu) {
    int wid  = blockIdx.x * 4 + (threadIdx.x >> 6);
    int lane = threadIdx.x & 63;
    const int NCH = BB * TT;
    const int NQU = BB * JJ;
    if (wid >= NCH + NQU) return;
    const float* base;
    const float* ws;
    float* outp;
    int idx;
    if (wid < NCH) { idx = wid;       base = C + (size_t)idx * DD; ws = w;      outp = ch; }
    else           { idx = wid - NCH; base = Q + (size_t)idx * DD; ws = w + DD; outp = qu; }
    float4 x  = *(const float4*)(base + lane * 4);
    float4 wv = *(const float4*)(ws   + lane * 4);
    float v = x.x * wv.x + x.y * wv.y + x.z * wv.z + x.w * wv.w;
    #pragma unroll
    for (int off = 32; off; off >>= 1) v += __shfl_xor(v, off, 64);
    if (lane == 0) outp[idx] = v;
}

// ---------------------------------------------------------------------------
// K2: S[b,t,j] = ch + qu + sum_d (C*w_hu)[t,d]*Q[j,d]; fused row-softmax stats
// Block: 64 t x 128 j tile. Thread grid 16(ty:t)x16(tx:j), 4x8 acc/thread.
// LDS tiles stored k-major so inner loop is ds_read_b128.
// ---------------------------------------------------------------------------
__global__ __launch_bounds__(256) void k_S(const float* __restrict__ C,
                                           const float* __restrict__ Q,
                                           const float* __restrict__ w,
                                           const float* __restrict__ ch,
                                           const float* __restrict__ qu,
                                           float* __restrict__ Sg,
                                           float* __restrict__ rowmax,
                                           float* __restrict__ rowsum) {
    const int b  = blockIdx.y;
    const int t0 = blockIdx.x * 64;
    const int tid = threadIdx.x;
    __shared__ float sA[32][68];    // [k][t]  (Cw tile, transposed)
    __shared__ float sB[32][132];   // [k][j]  (Q tile, transposed)
    const float* whu = w + 2 * DD;
    const float* Cb = C + ((size_t)b * TT + t0) * DD;
    const float* Qb = Q + (size_t)b * JJ * DD;

    const int ty = tid >> 4, tx = tid & 15;
    float acc[4][8];
    #pragma unroll
    for (int i = 0; i < 4; i++)
        #pragma unroll
        for (int u = 0; u < 8; u++) acc[i][u] = 0.f;

    for (int kc = 0; kc < DD; kc += 32) {
        __syncthreads();
        {   // stage A: 64 t x 32 k, multiply by w_hu on the way in
            int t  = tid >> 2;
            int dg = tid & 3;
            const float* cp = Cb + (size_t)t * DD + kc + dg * 8;
            const float* wp = whu + kc + dg * 8;
            float4 x0 = *(const float4*)(cp);
            float4 x1 = *(const float4*)(cp + 4);
            float4 w0 = *(const float4*)(wp);
            float4 w1 = *(const float4*)(wp + 4);
            int kb = dg * 8;
            sA[kb + 0][t] = x0.x * w0.x;
            sA[kb + 1][t] = x0.y * w0.y;
            sA[kb + 2][t] = x0.z * w0.z;
            sA[kb + 3][t] = x0.w * w0.w;
            sA[kb + 4][t] = x1.x * w1.x;
            sA[kb + 5][t] = x1.y * w1.y;
            sA[kb + 6][t] = x1.z * w1.z;
            sA[kb + 7][t] = x1.w * w1.w;
        }
        {   // stage B: 128 j x 32 k
            int j  = tid >> 1;
            int dg = tid & 1;
            const float* qp = Qb + (size_t)j * DD + kc + dg * 16;
            int kb = dg * 16;
            #pragma unroll
            for (int q = 0; q < 4; q++) {
                float4 v = *(const float4*)(qp + q * 4);
                sB[kb + q * 4 + 0][j] = v.x;
                sB[kb + q * 4 + 1][j] = v.y;
                sB[kb + q * 4 + 2][j] = v.z;
                sB[kb + q * 4 + 3][j] = v.w;
            }
        }
        __syncthreads();
        #pragma unroll
        for (int k = 0; k < 32; k++) {
            float4 a4  = *(const float4*)&sA[k][ty * 4];
            float4 b04 = *(const float4*)&sB[k][tx * 8];
            float4 b14 = *(const float4*)&sB[k][tx * 8 + 4];
            float av[4] = {a4.x, a4.y, a4.z, a4.w};
            float bv[8] = {b04.x, b04.y, b04.z, b04.w, b14.x, b14.y, b14.z, b14.w};
            #pragma unroll
            for (int i = 0; i < 4; i++)
                #pragma unroll
                for (int u = 0; u < 8; u++)
                    acc[i][u] = fmaf(av[i], bv[u], acc[i][u]);
        }
    }

    // epilogue: add ch/qu, write S, fused row max/sumexp (reduce over tx group)
    const int tg0 = b * TT + t0;
    float chv[4];
    #pragma unroll
    for (int i = 0; i < 4; i++) chv[i] = ch[tg0 + ty * 4 + i];
    float quv[8];
    #pragma unroll
    for (int u = 0; u < 8; u++) quv[u] = qu[b * JJ + tx * 8 + u];
    float* Sb = Sg + (size_t)tg0 * JJ;
    #pragma unroll
    for (int i = 0; i < 4; i++) {
        int t = ty * 4 + i;
        float vals[8];
        float m = -1e30f;
        #pragma unroll
        for (int u = 0; u < 8; u++) {
            vals[u] = acc[i][u] + chv[i] + quv[u];
            m = fmaxf(m, vals[u]);
        }
        #pragma unroll
        for (int off = 1; off < 16; off <<= 1) m = fmaxf(m, __shfl_xor(m, off, 64));
        float s = 0.f;
        #pragma unroll
        for (int u = 0; u < 8; u++) s += __expf(vals[u] - m);
        #pragma unroll
        for (int off = 1; off < 16; off <<= 1) s += __shfl_xor(s, off, 64);
        float4 o0 = make_float4(vals[0], vals[1], vals[2], vals[3]);
        float4 o1 = make_float4(vals[4], vals[5], vals[6], vals[7]);
        *(float4*)(Sb + (size_t)t * JJ + tx * 8)     = o0;
        *(float4*)(Sb + (size_t)t * JJ + tx * 8 + 4) = o1;
        if (tx == 0) { rowmax[tg0 + t] = m; rowsum[tg0 + t] = s; }
    }
}

// ---------------------------------------------------------------------------
// K3: column-softmax partials over t chunks of 32 (online max/sumexp)
// ---------------------------------------------------------------------------
__global__ __launch_bounds__(128) void k_colpart(const float* __restrict__ Sg,
                                                 float* __restrict__ pm,
                                                 float* __restrict__ ps) {
    int b = blockIdx.x >> 5;
    int c = blockIdx.x & 31;
    int j = threadIdx.x;
    const float* Sp = Sg + ((size_t)(b * TT + c * 32)) * JJ + j;
    float m = -1e30f, s = 0.f;
    #pragma unroll 4
    for (int k = 0; k < 32; k++) {
        float v = Sp[(size_t)k * JJ];
        float nm = fmaxf(m, v);
        s = s * __expf(m - nm) + __expf(v - nm);
        m = nm;
    }
    pm[(size_t)blockIdx.x * JJ + j] = m;
    ps[(size_t)blockIdx.x * JJ + j] = s;
}

__global__ __launch_bounds__(128) void k_colred(const float* __restrict__ pm,
                                                const float* __restrict__ ps,
                                                float* __restrict__ colmax,
                                                float* __restrict__ colsum) {
    int b = blockIdx.x;
    int j = threadIdx.x;
    float m = -1e30f;
    #pragma unroll 4
    for (int c = 0; c < 32; c++) m = fmaxf(m, pm[(size_t)(b * 32 + c) * JJ + j]);
    float s = 0.f;
    #pragma unroll 4
    for (int c = 0; c < 32; c++) s += ps[(size_t)(b * 32 + c) * JJ + j] * __expf(pm[(size_t)(b * 32 + c) * JJ + j] - m);
    colmax[b * JJ + j] = m;
    colsum[b * JJ + j] = s;
}

// ---------------------------------------------------------------------------
// K4: tmp[b,j,d] = (1/colsum[j]) * sum_t exp(S[t,j]-colmax[j]) * C[t,d]
// Block tile 64 j x 64 d, K loop over t in chunks of 32.
// ---------------------------------------------------------------------------
__global__ __launch_bounds__(256) void k_tmp(const float* __restrict__ Sg,
                                             const float* __restrict__ C,
                                             const float* __restrict__ colmax,
                                             const float* __restrict__ colsum,
                                             float* __restrict__ tmpO) {
    const int b  = blockIdx.y;
    const int jc = blockIdx.x >> 2;
    const int dc = blockIdx.x & 3;
    const int j0 = jc * 64, d0 = dc * 64;
    const int tid = threadIdx.x;
    __shared__ float sE[32][68];   // [k(t)][j]
    __shared__ float sC[32][68];   // [k(t)][d]
    const int ty = tid >> 4, tx = tid & 15;
    const int sk = tid >> 3, sg = tid & 7;
    float cmv[8];
    #pragma unroll
    for (int u = 0; u < 8; u++) cmv[u] = colmax[b * JJ + j0 + sg * 8 + u];
    float acc[4][4];
    #pragma unroll
    for (int i = 0; i < 4; i++)
        #pragma unroll
        for (int u = 0; u < 4; u++) acc[i][u] = 0.f;

    for (int tc = 0; tc < TT; tc += 32) {
        __syncthreads();
        {
            const float* Sp = Sg + ((size_t)(b * TT + tc + sk)) * JJ + j0 + sg * 8;
            float4 v0 = *(const float4*)(Sp);
            float4 v1 = *(const float4*)(Sp + 4);
            float4 e0 = make_float4(__expf(v0.x - cmv[0]), __expf(v0.y - cmv[1]),
                                    __expf(v0.z - cmv[2]), __expf(v0.w - cmv[3]));
            float4 e1 = make_float4(__expf(v1.x - cmv[4]), __expf(v1.y - cmv[5]),
                                    __expf(v1.z - cmv[6]), __expf(v1.w - cmv[7]));
            *(float4*)&sE[sk][sg * 8]     = e0;
            *(float4*)&sE[sk][sg * 8 + 4] = e1;
            const float* Cp = C + ((size_t)(b * TT + tc + sk)) * DD + d0 + sg * 8;
            *(float4*)&sC[sk][sg * 8]     = *(const float4*)(Cp);
            *(float4*)&sC[sk][sg * 8 + 4] = *(const float4*)(Cp + 4);
        }
        __syncthreads();
        #pragma unroll
        for (int k = 0; k < 32; k++) {
            float4 a4 = *(const float4*)&sE[k][ty * 4];
            float4 b4 = *(const float4*)&sC[k][tx * 4];
            float av[4] = {a4.x, a4.y, a4.z, a4.w};
            float bv[4] = {b4.x, b4.y, b4.z, b4.w};
            #pragma unroll
            for (int i = 0; i < 4; i++)
                #pragma unroll
                for (int u = 0; u < 4; u++)
                    acc[i][u] = fmaf(av[i], bv[u], acc[i][u]);
        }
    }
    #pragma unroll
    for (int i = 0; i < 4; i++) {
        int j = j0 + ty * 4 + i;
        float r = 1.0f / colsum[b * JJ + j];
        float4 o = make_float4(acc[i][0] * r, acc[i][1] * r, acc[i][2] * r, acc[i][3] * r);
        *(float4*)(tmpO + ((size_t)(b * JJ + j)) * DD + d0 + tx * 4) = o;
    }
}

// ---------------------------------------------------------------------------
// K5: A = P·Q, Bm = P·tmp with P = exp(S-rowmax)/rowsum; write concat output.
// Block: 16 t x 256 d; thread grid 8(ty:2t) x 32(tx: 2x float4 of d).
// ---------------------------------------------------------------------------
__global__ __launch_bounds__(256) void k_out(const float* __restrict__ Sg,
                                             const float* __restrict__ Q,
                                             const float* __restrict__ tmpI,
                                             const float* __restrict__ C,
                                             const float* __restrict__ rowmax,
                                             const float* __restrict__ rowsum,
                                             float* __restrict__ out) {
    const int b  = blockIdx.y;
    const int t0 = blockIdx.x * 16;
    const int tid = threadIdx.x;
    __shared__ float sP[16][132];   // [t][j]
    __shared__ float sQ[16][260];   // [j][d]
    __shared__ float sT[16][260];   // [j][d]

    {   // stage P once: 16 t x 128 j
        int t = tid >> 4, g = tid & 15;
        const float* Sp = Sg + ((size_t)(b * TT + t0 + t)) * JJ + g * 8;
        float m = rowmax[b * TT + t0 + t];
        float r = 1.0f / rowsum[b * TT + t0 + t];
        float4 v0 = *(const float4*)(Sp);
        float4 v1 = *(const float4*)(Sp + 4);
        float4 p0 = make_float4(__expf(v0.x - m) * r, __expf(v0.y - m) * r,
                                __expf(v0.z - m) * r, __expf(v0.w - m) * r);
        float4 p1 = make_float4(__expf(v1.x - m) * r, __expf(v1.y - m) * r,
                                __expf(v1.z - m) * r, __expf(v1.w - m) * r);
        *(float4*)&sP[t][g * 8]     = p0;
        *(float4*)&sP[t][g * 8 + 4] = p1;
    }

    const int ty = tid >> 5, tx = tid & 31;
    float aA[2][2][4], aB[2][2][4];
    #pragma unroll
    for (int i = 0; i < 2; i++)
        #pragma unroll
        for (int g = 0; g < 2; g++)
            #pragma unroll
            for (int u = 0; u < 4; u++) { aA[i][g][u] = 0.f; aB[i][g][u] = 0.f; }

    const int sj = tid >> 4, sg = tid & 15;
    for (int jc = 0; jc < JJ; jc += 16) {
        __syncthreads();
        {   // stage Q and tmp chunk: 16 j x 256 d
            const float* Qp = Q    + ((size_t)(b * JJ + jc + sj)) * DD + sg * 16;
            const float* Tp = tmpI + ((size_t)(b * JJ + jc + sj)) * DD + sg * 16;
            #pragma unroll
            for (int q = 0; q < 4; q++) {
                *(float4*)&sQ[sj][sg * 16 + q * 4] = *(const float4*)(Qp + q * 4);
                *(float4*)&sT[sj][sg * 16 + q * 4] = *(const float4*)(Tp + q * 4);
            }
        }
        __syncthreads();
        #pragma unroll
        for (int k = 0; k < 16; k++) {
            float pv[2];
            pv[0] = sP[ty * 2 + 0][jc + k];
            pv[1] = sP[ty * 2 + 1][jc + k];
            float4 q0 = *(const float4*)&sQ[k][tx * 4];
            float4 q1 = *(const float4*)&sQ[k][128 + tx * 4];
            float4 u0 = *(const float4*)&sT[k][tx * 4];
            float4 u1 = *(const float4*)&sT[k][128 + tx * 4];
            float qv[2][4] = {{q0.x, q0.y, q0.z, q0.w}, {q1.x, q1.y, q1.z, q1.w}};
            float uv[2][4] = {{u0.x, u0.y, u0.z, u0.w}, {u1.x, u1.y, u1.z, u1.w}};
            #pragma unroll
            for (int i = 0; i < 2; i++)
                #pragma unroll
                for (int g = 0; g < 2; g++)
                    #pragma unroll
                    for (int u = 0; u < 4; u++) {
                        aA[i][g][u] = fmaf(pv[i], qv[g][u], aA[i][g][u]);
                        aB[i][g][u] = fmaf(pv[i], uv[g][u], aB[i][g][u]);
                    }
        }
    }

    // epilogue: out = [C, A, C*A, C*Bm]
    #pragma unroll
    for (int i = 0; i < 2; i++) {
        int t = t0 + ty * 2 + i;
        const float* Cp = C + ((size_t)(b * TT + t)) * DD;
        float* op = out + ((size_t)(b * TT + t)) * (4 * DD);
        #pragma unroll
        for (int g = 0; g < 2; g++) {
            int d = g * 128 + tx * 4;
            float4 c = *(const float4*)(Cp + d);
            float4 a = make_float4(aA[i][g][0], aA[i][g][1], aA[i][g][2], aA[i][g][3]);
            float4 bm = make_float4(aB[i][g][0], aB[i][g][1], aB[i][g][2], aB[i][g][3]);
            *(float4*)(op + d)            = c;
            *(float4*)(op + DD + d)       = a;
            *(float4*)(op + 2 * DD + d)   = make_float4(c.x * a.x,  c.y * a.y,  c.z * a.z,  c.w * a.w);
            *(float4*)(op + 3 * DD + d)   = make_float4(c.x * bm.x, c.y * bm.y, c.z * bm.z, c.w * bm.w);
        }
    }
}

// ---------------------------------------------------------------------------
extern "C" void kernel_launch(void* const* d_in, const int* in_sizes, int n_in,
                              void* d_out, int out_size, void* d_ws, size_t ws_size,
                              hipStream_t stream) {
    const float* C = (const float*)d_in[0];
    const float* Q = (const float*)d_in[1];
    const float* w = (const float*)d_in[2];
    float* out = (float*)d_out;
    float* ws = (float*)d_ws;

    float* Sg     = ws;                               // B*T*J
    float* tmpB   = Sg + (size_t)BB * TT * JJ;        // B*J*D
    float* ch     = tmpB + (size_t)BB * JJ * DD;      // B*T
    float* qu     = ch + BB * TT;                     // B*J
    float* rowmax = qu + BB * JJ;                     // B*T
    float* rowsum = rowmax + BB * TT;                 // B*T
    float* colmax = rowsum + BB * TT;                 // B*J
    float* colsum = colmax + BB * JJ;                 // B*J
    float* pm     = colsum + BB * JJ;                 // B*32*J
    float* ps     = pm + (size_t)BB * 32 * JJ;        // B*32*J

    const int nrows = BB * TT + BB * JJ;              // 36864 rows, 4 waves/block
    k_rowdots<<<dim3((nrows + 3) / 4), dim3(256), 0, stream>>>(C, Q, w, ch, qu);
    k_S      <<<dim3(TT / 64, BB), dim3(256), 0, stream>>>(C, Q, w, ch, qu, Sg, rowmax, rowsum);
    k_colpart<<<dim3(BB * 32), dim3(128), 0, stream>>>(Sg, pm, ps);
    k_colred <<<dim3(BB), dim3(128), 0, stream>>>(pm, ps, colmax, colsum);
    k_tmp    <<<dim3(8, BB), dim3(256), 0, stream>>>(Sg, C, colmax, colsum, tmpB);
    k_out    <<<dim3(TT / 16, BB), dim3(256), 0, stream>>>(Sg, Q, tmpB, C, rowmax, rowsum, out);
}

// Round 3
// 158.418 us; speedup vs baseline: 1.2885x; 1.2885x over previous
//
#include <hip/hip_runtime.h>
#include <math.h>

#define BB 32
#define TT 1024
#define JJ 128
#define DD 256

typedef unsigned short u16;
typedef short s16x8 __attribute__((ext_vector_type(8)));
typedef float f32x4 __attribute__((ext_vector_type(4)));

#define MFMA_BF16(a, b, c) __builtin_amdgcn_mfma_f32_16x16x32_bf16((a), (b), (c), 0, 0, 0)

__device__ inline u16 f2bf(float f) {
    unsigned int u = __float_as_uint(f);
    u += 0x7FFFu + ((u >> 16) & 1u);
    return (u16)(u >> 16);
}
__device__ inline float bf2f(u16 h) {
    return __uint_as_float(((unsigned int)h) << 16);
}

// ---------------------------------------------------------------------------
// K1: ch[b,t] = C[b,t,:]·w_h ; qu[b,j] = Q[b,j,:]·w_u   (one wave per row)
// ---------------------------------------------------------------------------
__global__ __launch_bounds__(256) void k_rowdots(const float* __restrict__ C,
                                                 const float* __restrict__ Q,
                                                 const float* __restrict__ w,
                                                 float* __restrict__ ch,
                                                 float* __restrict__ qu) {
    int wid  = blockIdx.x * 4 + (threadIdx.x >> 6);
    int lane = threadIdx.x & 63;
    const int NCH = BB * TT;
    const int NQU = BB * JJ;
    if (wid >= NCH + NQU) return;
    const float* base;
    const float* ws;
    float* outp;
    int idx;
    if (wid < NCH) { idx = wid;       base = C + (size_t)idx * DD; ws = w;      outp = ch; }
    else           { idx = wid - NCH; base = Q + (size_t)idx * DD; ws = w + DD; outp = qu; }
    float4 x  = *(const float4*)(base + lane * 4);
    float4 wv = *(const float4*)(ws   + lane * 4);
    float v = x.x * wv.x + x.y * wv.y + x.z * wv.z + x.w * wv.w;
    #pragma unroll
    for (int off = 32; off; off >>= 1) v += __shfl_xor(v, off, 64);
    if (lane == 0) outp[idx] = v;
}

// ---------------------------------------------------------------------------
// K1b: Qt[b,d,j] = bf16(Q[b,j,d])  (transposed, j contiguous, for MFMA B-op)
// ---------------------------------------------------------------------------
__global__ __launch_bounds__(256) void k_qtrans(const float* __restrict__ Q,
                                                u16* __restrict__ Qt) {
    const int b  = blockIdx.y;
    const int d0 = blockIdx.x * 64;
    const int tid = threadIdx.x;
    __shared__ float sT[64][136];   // [d][j] fp32
    const int jr = tid >> 4;
    const int dq = (tid & 15) * 4;
    #pragma unroll
    for (int jj = 0; jj < 8; jj++) {
        int j = jj * 16 + jr;
        float4 v = *(const float4*)&Q[((size_t)b * JJ + j) * DD + d0 + dq];
        sT[dq + 0][j] = v.x;
        sT[dq + 1][j] = v.y;
        sT[dq + 2][j] = v.z;
        sT[dq + 3][j] = v.w;
    }
    __syncthreads();
    #pragma unroll
    for (int i = 0; i < 4; i++) {
        int c = tid + 256 * i;          // 1024 chunks of 8
        int d = c >> 4, j0 = (c & 15) * 8;
        uint4 pk;
        pk.x = (unsigned)f2bf(sT[d][j0 + 0]) | ((unsigned)f2bf(sT[d][j0 + 1]) << 16);
        pk.y = (unsigned)f2bf(sT[d][j0 + 2]) | ((unsigned)f2bf(sT[d][j0 + 3]) << 16);
        pk.z = (unsigned)f2bf(sT[d][j0 + 4]) | ((unsigned)f2bf(sT[d][j0 + 5]) << 16);
        pk.w = (unsigned)f2bf(sT[d][j0 + 6]) | ((unsigned)f2bf(sT[d][j0 + 7]) << 16);
        *(uint4*)&Qt[((size_t)b * DD + d0 + d) * JJ + j0] = pk;
    }
}

// ---------------------------------------------------------------------------
// K2: S = ch + qu + (C*w_hu)·Q^T (fp32 core). Epilogue: row stats (rowmax,
// 1/rowsum), writes X = exp(S - rowmax) as bf16, and per-block COLUMN
// max/sumexp partials (pm/ps) -> k_colpart eliminated.
// ---------------------------------------------------------------------------
__global__ __launch_bounds__(256) void k_S(const float* __restrict__ C,
                                           const float* __restrict__ Q,
                                           const float* __restrict__ w,
                                           const float* __restrict__ ch,
                                           const float* __restrict__ qu,
                                           u16* __restrict__ Xg,
                                           float* __restrict__ rowmax,
                                           float* __restrict__ rowrcp,
                                           float* __restrict__ pm,
                                           float* __restrict__ ps) {
    const int b  = blockIdx.y;
    const int bx = blockIdx.x;
    const int t0 = bx * 64;
    const int tid = threadIdx.x;
    __shared__ float sA[32][68];    // [k][t]
    __shared__ float sB[32][132];   // [k][j]
    __shared__ float sRed[16][128];
    __shared__ float sCMb[128];
    const float* whu = w + 2 * DD;
    const float* Cb = C + ((size_t)b * TT + t0) * DD;
    const float* Qb = Q + (size_t)b * JJ * DD;

    const int ty = tid >> 4, tx = tid & 15;
    float acc[4][8];
    #pragma unroll
    for (int i = 0; i < 4; i++)
        #pragma unroll
        for (int u = 0; u < 8; u++) acc[i][u] = 0.f;

    for (int kc = 0; kc < DD; kc += 32) {
        __syncthreads();
        {   // stage A: 64 t x 32 k with w_hu folded
            int t  = tid >> 2;
            int dg = tid & 3;
            const float* cp = Cb + (size_t)t * DD + kc + dg * 8;
            const float* wp = whu + kc + dg * 8;
            float4 x0 = *(const float4*)(cp);
            float4 x1 = *(const float4*)(cp + 4);
            float4 w0 = *(const float4*)(wp);
            float4 w1 = *(const float4*)(wp + 4);
            int kb = dg * 8;
            sA[kb + 0][t] = x0.x * w0.x;
            sA[kb + 1][t] = x0.y * w0.y;
            sA[kb + 2][t] = x0.z * w0.z;
            sA[kb + 3][t] = x0.w * w0.w;
            sA[kb + 4][t] = x1.x * w1.x;
            sA[kb + 5][t] = x1.y * w1.y;
            sA[kb + 6][t] = x1.z * w1.z;
            sA[kb + 7][t] = x1.w * w1.w;
        }
        {   // stage B: 128 j x 32 k
            int j  = tid >> 1;
            int dg = tid & 1;
            const float* qp = Qb + (size_t)j * DD + kc + dg * 16;
            int kb = dg * 16;
            #pragma unroll
            for (int q = 0; q < 4; q++) {
                float4 v = *(const float4*)(qp + q * 4);
                sB[kb + q * 4 + 0][j] = v.x;
                sB[kb + q * 4 + 1][j] = v.y;
                sB[kb + q * 4 + 2][j] = v.z;
                sB[kb + q * 4 + 3][j] = v.w;
            }
        }
        __syncthreads();
        #pragma unroll
        for (int k = 0; k < 32; k++) {
            float4 a4  = *(const float4*)&sA[k][ty * 4];
            float4 b04 = *(const float4*)&sB[k][tx * 8];
            float4 b14 = *(const float4*)&sB[k][tx * 8 + 4];
            float av[4] = {a4.x, a4.y, a4.z, a4.w};
            float bv[8] = {b04.x, b04.y, b04.z, b04.w, b14.x, b14.y, b14.z, b14.w};
            #pragma unroll
            for (int i = 0; i < 4; i++)
                #pragma unroll
                for (int u = 0; u < 8; u++)
                    acc[i][u] = fmaf(av[i], bv[u], acc[i][u]);
        }
    }

    // ---- epilogue ----
    const int tg0 = b * TT + t0;
    float chv[4];
    #pragma unroll
    for (int i = 0; i < 4; i++) chv[i] = ch[tg0 + ty * 4 + i];
    float quv[8];
    #pragma unroll
    for (int u = 0; u < 8; u++) quv[u] = qu[b * JJ + tx * 8 + u];

    #pragma unroll
    for (int i = 0; i < 4; i++) {
        int t = ty * 4 + i;
        float m = -1e30f;
        #pragma unroll
        for (int u = 0; u < 8; u++) {
            acc[i][u] += chv[i] + quv[u];
            m = fmaxf(m, acc[i][u]);
        }
        #pragma unroll
        for (int off = 1; off < 16; off <<= 1) m = fmaxf(m, __shfl_xor(m, off, 64));
        float xv[8];
        float s = 0.f;
        #pragma unroll
        for (int u = 0; u < 8; u++) { xv[u] = __expf(acc[i][u] - m); s += xv[u]; }
        #pragma unroll
        for (int off = 1; off < 16; off <<= 1) s += __shfl_xor(s, off, 64);
        uint4 pk;
        pk.x = (unsigned)f2bf(xv[0]) | ((unsigned)f2bf(xv[1]) << 16);
        pk.y = (unsigned)f2bf(xv[2]) | ((unsigned)f2bf(xv[3]) << 16);
        pk.z = (unsigned)f2bf(xv[4]) | ((unsigned)f2bf(xv[5]) << 16);
        pk.w = (unsigned)f2bf(xv[6]) | ((unsigned)f2bf(xv[7]) << 16);
        *(uint4*)&Xg[((size_t)tg0 + t) * JJ + tx * 8] = pk;
        if (tx == 0) { rowmax[tg0 + t] = m; rowrcp[tg0 + t] = 1.0f / s; }
    }

    // column partials over this block's 64 t
    #pragma unroll
    for (int u = 0; u < 8; u++) {
        float cm = fmaxf(fmaxf(acc[0][u], acc[1][u]), fmaxf(acc[2][u], acc[3][u]));
        sRed[ty][tx * 8 + u] = cm;
    }
    __syncthreads();
    if (tid < 128) {
        float m = -1e30f;
        #pragma unroll
        for (int r = 0; r < 16; r++) m = fmaxf(m, sRed[r][tid]);
        sCMb[tid] = m;
        pm[((size_t)b * 16 + bx) * JJ + tid] = m;
    }
    __syncthreads();
    #pragma unroll
    for (int u = 0; u < 8; u++) {
        float bm = sCMb[tx * 8 + u];
        float s = __expf(acc[0][u] - bm) + __expf(acc[1][u] - bm) +
                  __expf(acc[2][u] - bm) + __expf(acc[3][u] - bm);
        sRed[ty][tx * 8 + u] = s;
    }
    __syncthreads();
    if (tid < 128) {
        float s = 0.f;
        #pragma unroll
        for (int r = 0; r < 16; r++) s += sRed[r][tid];
        ps[((size_t)b * 16 + bx) * JJ + tid] = s;
    }
}

// ---------------------------------------------------------------------------
// K3: combine 16 per-block column partials -> colmax, 1/colsum
// ---------------------------------------------------------------------------
__global__ __launch_bounds__(128) void k_colred(const float* __restrict__ pm,
                                                const float* __restrict__ ps,
                                                float* __restrict__ colmax,
                                                float* __restrict__ colrcp) {
    int b = blockIdx.x;
    int j = threadIdx.x;
    float m = -1e30f;
    #pragma unroll
    for (int tb = 0; tb < 16; tb++) m = fmaxf(m, pm[((size_t)b * 16 + tb) * JJ + j]);
    float s = 0.f;
    #pragma unroll
    for (int tb = 0; tb < 16; tb++)
        s += ps[((size_t)b * 16 + tb) * JJ + j] * __expf(pm[((size_t)b * 16 + tb) * JJ + j] - m);
    colmax[b * JJ + j] = m;
    colrcp[b * JJ + j] = 1.0f / s;
}

// ---------------------------------------------------------------------------
// K4 (MFMA): tmpT[b,d,j] = sum_t [X[t,j]*exp(rowmax[t]-colmax[j])/colsum[j]] * C[t,d]
// A = G^T [j][t] (exp+scale folded in transpose staging), B = C^T [d][t].
// Block: full 128 j x 32 d, K-loop 64 t.
// ---------------------------------------------------------------------------
__global__ __launch_bounds__(256) void k_tmp(const u16* __restrict__ Xg,
                                             const float* __restrict__ C,
                                             const float* __restrict__ rowmax,
                                             const float* __restrict__ colmax,
                                             const float* __restrict__ colrcp,
                                             u16* __restrict__ Tt) {
    const int b  = blockIdx.y;
    const int d0 = blockIdx.x * 32;
    const int tid = threadIdx.x;
    __shared__ __align__(16) u16 sG[128 * 72];    // [j][t] stride 72
    __shared__ __align__(16) u16 sCt[32 * 72];    // [d][t] stride 72
    __shared__ float sCM[128], sRC[128];
    if (tid < 128) {
        sCM[tid] = colmax[b * JJ + tid];
        sRC[tid] = colrcp[b * JJ + tid];
    }
    const int lane = tid & 63, wv = tid >> 6;
    const int lr = lane & 15, lg = lane >> 4;
    f32x4 zero4 = {0.f, 0.f, 0.f, 0.f};
    f32x4 acc[2][2];
    acc[0][0] = zero4; acc[0][1] = zero4; acc[1][0] = zero4; acc[1][1] = zero4;

    for (int tt = 0; tt < TT; tt += 64) {
        __syncthreads();
        // stage G^T with exp + 1/colsum folded
        #pragma unroll
        for (int i = 0; i < 4; i++) {
            int c = tid + 256 * i;
            int trow = c >> 4, j0 = (c & 15) * 8;
            int gt = tt + trow;
            float rm = rowmax[b * TT + gt];
            uint4 xv = *(const uint4*)&Xg[((size_t)b * TT + gt) * JJ + j0];
            const u16* xp = (const u16*)&xv;
            #pragma unroll
            for (int u = 0; u < 8; u++) {
                float x = bf2f(xp[u]);
                float g = x * __expf(rm - sCM[j0 + u]) * sRC[j0 + u];
                sG[(j0 + u) * 72 + trow] = f2bf(g);
            }
        }
        // stage C^T
        #pragma unroll
        for (int i = 0; i < 2; i++) {
            int c = tid + 256 * i;
            int trow = c >> 3, dcl = (c & 7) * 4;
            float4 cv = *(const float4*)&C[((size_t)b * TT + tt + trow) * DD + d0 + dcl];
            sCt[(dcl + 0) * 72 + trow] = f2bf(cv.x);
            sCt[(dcl + 1) * 72 + trow] = f2bf(cv.y);
            sCt[(dcl + 2) * 72 + trow] = f2bf(cv.z);
            sCt[(dcl + 3) * 72 + trow] = f2bf(cv.w);
        }
        __syncthreads();
        #pragma unroll
        for (int ks = 0; ks < 2; ks++) {
            int kc = ks * 32 + lg * 8;
            s16x8 a0 = *(const s16x8*)&sG[(wv * 32 + lr) * 72 + kc];
            s16x8 a1 = *(const s16x8*)&sG[(wv * 32 + 16 + lr) * 72 + kc];
            s16x8 b0 = *(const s16x8*)&sCt[(lr) * 72 + kc];
            s16x8 b1 = *(const s16x8*)&sCt[(16 + lr) * 72 + kc];
            acc[0][0] = MFMA_BF16(a0, b0, acc[0][0]);
            acc[0][1] = MFMA_BF16(a0, b1, acc[0][1]);
            acc[1][0] = MFMA_BF16(a1, b0, acc[1][0]);
            acc[1][1] = MFMA_BF16(a1, b1, acc[1][1]);
        }
    }
    #pragma unroll
    for (int mr = 0; mr < 2; mr++)
        #pragma unroll
        for (int nr = 0; nr < 2; nr++)
            #pragma unroll
            for (int reg = 0; reg < 4; reg++) {
                int j = wv * 32 + mr * 16 + lg * 4 + reg;
                int d = d0 + nr * 16 + lr;
                Tt[((size_t)b * DD + d) * JJ + j] = f2bf(acc[mr][nr][reg]);
            }
}

// ---------------------------------------------------------------------------
// K5 (MFMA): A = (X/rowsum)·Q, Bm = (X/rowsum)·tmp; out = [C, A, C*A, C*Bm].
// Block: 64 t x 64 d; K = 128 (j) staged once. 4 waves, each 32t x 32d x 2 GEMMs.
// ---------------------------------------------------------------------------
__global__ __launch_bounds__(256) void k_out(const u16* __restrict__ Xg,
                                             const u16* __restrict__ Qt,
                                             const u16* __restrict__ Tt,
                                             const float* __restrict__ C,
                                             const float* __restrict__ rowrcp,
                                             float* __restrict__ out) {
    const int b  = blockIdx.y;
    const int tc = blockIdx.x >> 2, dc = blockIdx.x & 3;
    const int t0 = tc * 64, d0 = dc * 64;
    const int tid = threadIdx.x;
    __shared__ __align__(16) u16 sX[64 * 136];
    __shared__ __align__(16) u16 sQ[64 * 136];
    __shared__ __align__(16) u16 sT[64 * 136];
    const size_t xbase = ((size_t)b * TT + t0) * JJ;
    const size_t qbase = ((size_t)b * DD + d0) * JJ;
    #pragma unroll
    for (int i = 0; i < 4; i++) {
        int c = tid + 256 * i;
        int row = c >> 4, col = (c & 15) * 8;
        int lo = row * 136 + col;
        *(uint4*)&sX[lo] = *(const uint4*)&Xg[xbase + (size_t)row * JJ + col];
        *(uint4*)&sQ[lo] = *(const uint4*)&Qt[qbase + (size_t)row * JJ + col];
        *(uint4*)&sT[lo] = *(const uint4*)&Tt[qbase + (size_t)row * JJ + col];
    }
    __syncthreads();
    const int lane = tid & 63, wv = tid >> 6;
    const int wm = wv >> 1, wn = wv & 1;
    const int lr = lane & 15, lg = lane >> 4;
    f32x4 zero4 = {0.f, 0.f, 0.f, 0.f};
    f32x4 accA[2][2], accB[2][2];
    #pragma unroll
    for (int mr = 0; mr < 2; mr++)
        #pragma unroll
        for (int nr = 0; nr < 2; nr++) { accA[mr][nr] = zero4; accB[mr][nr] = zero4; }

    #pragma unroll
    for (int ks = 0; ks < 4; ks++) {
        int kc = ks * 32 + lg * 8;
        s16x8 a0 = *(const s16x8*)&sX[(wm * 32 + lr) * 136 + kc];
        s16x8 a1 = *(const s16x8*)&sX[(wm * 32 + 16 + lr) * 136 + kc];
        s16x8 q0 = *(const s16x8*)&sQ[(wn * 32 + lr) * 136 + kc];
        s16x8 q1 = *(const s16x8*)&sQ[(wn * 32 + 16 + lr) * 136 + kc];
        s16x8 u0 = *(const s16x8*)&sT[(wn * 32 + lr) * 136 + kc];
        s16x8 u1 = *(const s16x8*)&sT[(wn * 32 + 16 + lr) * 136 + kc];
        accA[0][0] = MFMA_BF16(a0, q0, accA[0][0]);
        accA[0][1] = MFMA_BF16(a0, q1, accA[0][1]);
        accA[1][0] = MFMA_BF16(a1, q0, accA[1][0]);
        accA[1][1] = MFMA_BF16(a1, q1, accA[1][1]);
        accB[0][0] = MFMA_BF16(a0, u0, accB[0][0]);
        accB[0][1] = MFMA_BF16(a0, u1, accB[0][1]);
        accB[1][0] = MFMA_BF16(a1, u0, accB[1][0]);
        accB[1][1] = MFMA_BF16(a1, u1, accB[1][1]);
    }

    #pragma unroll
    for (int mr = 0; mr < 2; mr++) {
        #pragma unroll
        for (int reg = 0; reg < 4; reg++) {
            int t = t0 + wm * 32 + mr * 16 + lg * 4 + reg;
            float r = rowrcp[b * TT + t];
            const float* Cp = C + ((size_t)b * TT + t) * DD;
            float* op = out + ((size_t)b * TT + t) * (4 * DD);
            #pragma unroll
            for (int nr = 0; nr < 2; nr++) {
                int d = d0 + wn * 32 + nr * 16 + lr;
                float cv = Cp[d];
                float av = accA[mr][nr][reg] * r;
                float bv = accB[mr][nr][reg] * r;
                op[d]          = cv;
                op[DD + d]     = av;
                op[2 * DD + d] = cv * av;
                op[3 * DD + d] = cv * bv;
            }
        }
    }
}

// ---------------------------------------------------------------------------
extern "C" void kernel_launch(void* const* d_in, const int* in_sizes, int n_in,
                              void* d_out, int out_size, void* d_ws, size_t ws_size,
                              hipStream_t stream) {
    const float* C = (const float*)d_in[0];
    const float* Q = (const float*)d_in[1];
    const float* w = (const float*)d_in[2];
    float* out = (float*)d_out;
    float* p = (float*)d_ws;

    u16* Xg = (u16*)p;      p += (size_t)BB * TT * JJ / 2;   // bf16 X
    u16* Qt = (u16*)p;      p += (size_t)BB * DD * JJ / 2;   // bf16 Q^T
    u16* Tt = (u16*)p;      p += (size_t)BB * DD * JJ / 2;   // bf16 tmp^T
    float* ch     = p;      p += BB * TT;
    float* qu     = p;      p += BB * JJ;
    float* rowmax = p;      p += BB * TT;
    float* rowrcp = p;      p += BB * TT;
    float* colmax = p;      p += BB * JJ;
    float* colrcp = p;      p += BB * JJ;
    float* pm     = p;      p += (size_t)BB * 16 * JJ;
    float* ps     = p;      p += (size_t)BB * 16 * JJ;

    const int nrows = BB * TT + BB * JJ;
    k_rowdots<<<dim3((nrows + 3) / 4), dim3(256), 0, stream>>>(C, Q, w, ch, qu);
    k_qtrans <<<dim3(DD / 64, BB), dim3(256), 0, stream>>>(Q, Qt);
    k_S      <<<dim3(TT / 64, BB), dim3(256), 0, stream>>>(C, Q, w, ch, qu, Xg, rowmax, rowrcp, pm, ps);
    k_colred <<<dim3(BB), dim3(128), 0, stream>>>(pm, ps, colmax, colrcp);
    k_tmp    <<<dim3(DD / 32, BB), dim3(256), 0, stream>>>(Xg, C, rowmax, colmax, colrcp, Tt);
    k_out    <<<dim3(16 * 4, BB), dim3(256), 0, stream>>>(Xg, Qt, Tt, C, rowrcp, out);
}

// Round 4
// 128.250 us; speedup vs baseline: 1.5916x; 1.2352x over previous
//
#include <hip/hip_runtime.h>
#include <math.h>

#define BB 32
#define TT 1024
#define JJ 128
#define DD 256

typedef unsigned short u16;
typedef short s16x8 __attribute__((ext_vector_type(8)));
typedef float f32x4 __attribute__((ext_vector_type(4)));

#define MFMA_BF16(a, b, c) __builtin_amdgcn_mfma_f32_16x16x32_bf16((a), (b), (c), 0, 0, 0)

__device__ inline u16 f2bf(float f) {
    unsigned int u = __float_as_uint(f);
    u += 0x7FFFu + ((u >> 16) & 1u);
    return (u16)(u >> 16);
}
__device__ inline float bf2f(u16 h) {
    return __uint_as_float(((unsigned int)h) << 16);
}

// ---------------------------------------------------------------------------
// K1: ch[b,t] = C[b,t,:]·w_h ; qu[b,j] = Q[b,j,:]·w_u   (one wave per row)
// ---------------------------------------------------------------------------
__global__ __launch_bounds__(256) void k_rowdots(const float* __restrict__ C,
                                                 const float* __restrict__ Q,
                                                 const float* __restrict__ w,
                                                 float* __restrict__ ch,
                                                 float* __restrict__ qu) {
    int wid  = blockIdx.x * 4 + (threadIdx.x >> 6);
    int lane = threadIdx.x & 63;
    const int NCH = BB * TT;
    const int NQU = BB * JJ;
    if (wid >= NCH + NQU) return;
    const float* base;
    const float* ws;
    float* outp;
    int idx;
    if (wid < NCH) { idx = wid;       base = C + (size_t)idx * DD; ws = w;      outp = ch; }
    else           { idx = wid - NCH; base = Q + (size_t)idx * DD; ws = w + DD; outp = qu; }
    float4 x  = *(const float4*)(base + lane * 4);
    float4 wv = *(const float4*)(ws   + lane * 4);
    float v = x.x * wv.x + x.y * wv.y + x.z * wv.z + x.w * wv.w;
    #pragma unroll
    for (int off = 32; off; off >>= 1) v += __shfl_xor(v, off, 64);
    if (lane == 0) outp[idx] = v;
}

// ---------------------------------------------------------------------------
// K1b: Qt[b,d,j] (bf16, for k_out B-op) + Qhi/Qlo[b,j,d] (split bf16 for k_S)
// ---------------------------------------------------------------------------
__global__ __launch_bounds__(256) void k_qtrans(const float* __restrict__ Q,
                                                u16* __restrict__ Qt,
                                                u16* __restrict__ Qhi,
                                                u16* __restrict__ Qlo) {
    const int b  = blockIdx.y;
    const int d0 = blockIdx.x * 64;
    const int tid = threadIdx.x;
    __shared__ float sT[64][136];   // [d][j] fp32
    const int jr = tid >> 4;
    const int dq = (tid & 15) * 4;
    #pragma unroll
    for (int jj = 0; jj < 8; jj++) {
        int j = jj * 16 + jr;
        float4 v = *(const float4*)&Q[((size_t)b * JJ + j) * DD + d0 + dq];
        sT[dq + 0][j] = v.x;
        sT[dq + 1][j] = v.y;
        sT[dq + 2][j] = v.z;
        sT[dq + 3][j] = v.w;
        ushort4 h, l;
        h.x = f2bf(v.x); l.x = f2bf(v.x - bf2f(h.x));
        h.y = f2bf(v.y); l.y = f2bf(v.y - bf2f(h.y));
        h.z = f2bf(v.z); l.z = f2bf(v.z - bf2f(h.z));
        h.w = f2bf(v.w); l.w = f2bf(v.w - bf2f(h.w));
        *(ushort4*)&Qhi[((size_t)b * JJ + j) * DD + d0 + dq] = h;
        *(ushort4*)&Qlo[((size_t)b * JJ + j) * DD + d0 + dq] = l;
    }
    __syncthreads();
    #pragma unroll
    for (int i = 0; i < 4; i++) {
        int c = tid + 256 * i;          // 1024 chunks of 8
        int d = c >> 4, j0 = (c & 15) * 8;
        uint4 pk;
        pk.x = (unsigned)f2bf(sT[d][j0 + 0]) | ((unsigned)f2bf(sT[d][j0 + 1]) << 16);
        pk.y = (unsigned)f2bf(sT[d][j0 + 2]) | ((unsigned)f2bf(sT[d][j0 + 3]) << 16);
        pk.z = (unsigned)f2bf(sT[d][j0 + 4]) | ((unsigned)f2bf(sT[d][j0 + 5]) << 16);
        pk.w = (unsigned)f2bf(sT[d][j0 + 6]) | ((unsigned)f2bf(sT[d][j0 + 7]) << 16);
        *(uint4*)&Qt[((size_t)b * DD + d0 + d) * JJ + j0] = pk;
    }
}

// ---------------------------------------------------------------------------
// K2 (split-bf16 MFMA): S = ch + qu + (C*w_hu)·Q^T via hi/lo decomposition
// (3 MFMAs: hh + hl + lh, error ~2^-18). Tile 64t x 128j, K chunks of 64.
// Epilogue: S staged fp32 in LDS (union with GEMM tiles) -> row stats,
// column partials (pm/ps), X = exp(S - rowmax) bf16.
// ---------------------------------------------------------------------------
__global__ __launch_bounds__(256) void k_S(const float* __restrict__ C,
                                           const u16* __restrict__ Qhi,
                                           const u16* __restrict__ Qlo,
                                           const float* __restrict__ w,
                                           const float* __restrict__ ch,
                                           const float* __restrict__ qu,
                                           u16* __restrict__ Xg,
                                           float* __restrict__ rowmax,
                                           float* __restrict__ rowrcp,
                                           float* __restrict__ pm,
                                           float* __restrict__ ps) {
    const int b  = blockIdx.y;
    const int bx = blockIdx.x;
    const int t0 = bx * 64;
    const int tid = threadIdx.x;

    union SMem {
        struct { u16 Ah[64 * 72]; u16 Al[64 * 72]; u16 Bh[128 * 72]; u16 Bl[128 * 72]; } g;
        struct { float S[64 * 132]; float RM[64]; float PM2[256]; float PS2[256]; } e;
    };
    __shared__ __align__(16) SMem sm;
    __shared__ float sCH[64];
    __shared__ float sQU[128];

    if (tid < 64)  sCH[tid] = ch[(size_t)b * TT + t0 + tid];
    if (tid < 128) sQU[tid] = qu[b * JJ + tid];

    const float* whu = w + 2 * DD;
    const float* Cb  = C + ((size_t)b * TT + t0) * DD;

    const int lane = tid & 63, wv = tid >> 6;
    const int wm = wv >> 1, wn = wv & 1;
    const int lr = lane & 15, lg = lane >> 4;

    f32x4 zero4 = {0.f, 0.f, 0.f, 0.f};
    f32x4 acc[2][4];
    #pragma unroll
    for (int m = 0; m < 2; m++)
        #pragma unroll
        for (int n = 0; n < 4; n++) acc[m][n] = zero4;

    const int tA = tid >> 2, sA = (tid & 3) * 16;
    const int jB = tid >> 1, sB = (tid & 1) * 32;

    for (int kc = 0; kc < DD; kc += 64) {
        __syncthreads();
        {   // stage A: (C*w_hu)[64t][64k] -> hi/lo bf16
            const float* cp = Cb + (size_t)tA * DD + kc + sA;
            const float* wp = whu + kc + sA;
            float cc[16], ww[16];
            #pragma unroll
            for (int q = 0; q < 4; q++) {
                *(float4*)&cc[q * 4] = *(const float4*)(cp + q * 4);
                *(float4*)&ww[q * 4] = *(const float4*)(wp + q * 4);
            }
            u16 hi16[16], lo16[16];
            #pragma unroll
            for (int u = 0; u < 16; u++) {
                float v = cc[u] * ww[u];
                u16 h = f2bf(v);
                hi16[u] = h;
                lo16[u] = f2bf(v - bf2f(h));
            }
            int o = tA * 72 + sA;
            *(uint4*)&sm.g.Ah[o]     = *(uint4*)&hi16[0];
            *(uint4*)&sm.g.Ah[o + 8] = *(uint4*)&hi16[8];
            *(uint4*)&sm.g.Al[o]     = *(uint4*)&lo16[0];
            *(uint4*)&sm.g.Al[o + 8] = *(uint4*)&lo16[8];
        }
        {   // stage B: Qhi/Qlo[128j][64k] (pure copies)
            const uint4* qh = (const uint4*)&Qhi[((size_t)b * JJ + jB) * DD + kc + sB];
            const uint4* ql = (const uint4*)&Qlo[((size_t)b * JJ + jB) * DD + kc + sB];
            uint4* dh = (uint4*)&sm.g.Bh[jB * 72 + sB];
            uint4* dl = (uint4*)&sm.g.Bl[jB * 72 + sB];
            #pragma unroll
            for (int q = 0; q < 4; q++) { dh[q] = qh[q]; dl[q] = ql[q]; }
        }
        __syncthreads();
        #pragma unroll
        for (int ks = 0; ks < 2; ks++) {
            const int ko = ks * 32 + lg * 8;
            s16x8 ah[2], al[2], bh[4], bl[4];
            #pragma unroll
            for (int m = 0; m < 2; m++) {
                ah[m] = *(const s16x8*)&sm.g.Ah[(wm * 32 + m * 16 + lr) * 72 + ko];
                al[m] = *(const s16x8*)&sm.g.Al[(wm * 32 + m * 16 + lr) * 72 + ko];
            }
            #pragma unroll
            for (int n = 0; n < 4; n++) {
                bh[n] = *(const s16x8*)&sm.g.Bh[(wn * 64 + n * 16 + lr) * 72 + ko];
                bl[n] = *(const s16x8*)&sm.g.Bl[(wn * 64 + n * 16 + lr) * 72 + ko];
            }
            #pragma unroll
            for (int m = 0; m < 2; m++)
                #pragma unroll
                for (int n = 0; n < 4; n++) {
                    f32x4 t = acc[m][n];
                    t = MFMA_BF16(ah[m], bh[n], t);
                    t = MFMA_BF16(ah[m], bl[n], t);
                    t = MFMA_BF16(al[m], bh[n], t);
                    acc[m][n] = t;
                }
        }
    }

    // ---- epilogue ----
    __syncthreads();
    #pragma unroll
    for (int m = 0; m < 2; m++) {
        int row0 = wm * 32 + m * 16 + lg * 4;
        #pragma unroll
        for (int n = 0; n < 4; n++) {
            int col = wn * 64 + n * 16 + lr;
            float qv = sQU[col];
            #pragma unroll
            for (int reg = 0; reg < 4; reg++)
                sm.e.S[(row0 + reg) * 132 + col] = acc[m][n][reg] + sCH[row0 + reg] + qv;
        }
    }
    __syncthreads();
    {   // row stats: 4 threads per row
        int r = tid >> 2, s = tid & 3;
        float v[32];
        const float* Sr = &sm.e.S[r * 132 + s * 32];
        #pragma unroll
        for (int q = 0; q < 8; q++) *(float4*)&v[q * 4] = *(const float4*)&Sr[q * 4];
        float mx = v[0];
        #pragma unroll
        for (int u = 1; u < 32; u++) mx = fmaxf(mx, v[u]);
        mx = fmaxf(mx, __shfl_xor(mx, 1, 64));
        mx = fmaxf(mx, __shfl_xor(mx, 2, 64));
        float sum = 0.f;
        #pragma unroll
        for (int u = 0; u < 32; u++) sum += __expf(v[u] - mx);
        sum += __shfl_xor(sum, 1, 64);
        sum += __shfl_xor(sum, 2, 64);
        if (s == 0) {
            sm.e.RM[r] = mx;
            rowmax[(size_t)b * TT + t0 + r] = mx;
            rowrcp[(size_t)b * TT + t0 + r] = 1.0f / sum;
        }
    }
    {   // column partials (two t-halves per column)
        int j = tid & 127, h = tid >> 7;
        float cm = -1e30f;
        #pragma unroll
        for (int k = 0; k < 32; k++) cm = fmaxf(cm, sm.e.S[(h * 32 + k) * 132 + j]);
        float cs = 0.f;
        #pragma unroll
        for (int k = 0; k < 32; k++) cs += __expf(sm.e.S[(h * 32 + k) * 132 + j] - cm);
        sm.e.PM2[h * 128 + j] = cm;
        sm.e.PS2[h * 128 + j] = cs;
    }
    __syncthreads();
    if (tid < 128) {
        float m0 = sm.e.PM2[tid], m1 = sm.e.PM2[128 + tid];
        float M = fmaxf(m0, m1);
        float S2 = sm.e.PS2[tid] * __expf(m0 - M) + sm.e.PS2[128 + tid] * __expf(m1 - M);
        pm[((size_t)b * 16 + bx) * JJ + tid] = M;
        ps[((size_t)b * 16 + bx) * JJ + tid] = S2;
    }
    // X = exp(S - rowmax) bf16
    #pragma unroll
    for (int i = 0; i < 4; i++) {
        int c = tid + 256 * i;
        int row = c >> 4, j0 = (c & 15) * 8;
        float rm = sm.e.RM[row];
        float vv[8];
        *(float4*)&vv[0] = *(const float4*)&sm.e.S[row * 132 + j0];
        *(float4*)&vv[4] = *(const float4*)&sm.e.S[row * 132 + j0 + 4];
        u16 xp[8];
        #pragma unroll
        for (int u = 0; u < 8; u++) xp[u] = f2bf(__expf(vv[u] - rm));
        *(uint4*)&Xg[((size_t)b * TT + t0 + row) * JJ + j0] = *(uint4*)&xp[0];
    }
}

// ---------------------------------------------------------------------------
// K3: per-batch reduce: colmax/colsum from pm/ps; K_b = max_t rowmax;
// er[t] = exp(rowmax - K_b); ec[j] = exp(K_b - colmax)/colsum.
// ---------------------------------------------------------------------------
__global__ __launch_bounds__(256) void k_colred(const float* __restrict__ pm,
                                                const float* __restrict__ ps,
                                                const float* __restrict__ rowmax,
                                                float* __restrict__ er,
                                                float* __restrict__ ec) {
    const int b = blockIdx.x;
    const int tid = threadIdx.x;
    __shared__ float sW[4];
    float m = -1e30f;
    #pragma unroll
    for (int k = 0; k < 4; k++) m = fmaxf(m, rowmax[(size_t)b * TT + tid + 256 * k]);
    #pragma unroll
    for (int off = 32; off; off >>= 1) m = fmaxf(m, __shfl_xor(m, off, 64));
    if ((tid & 63) == 0) sW[tid >> 6] = m;
    __syncthreads();
    const float K = fmaxf(fmaxf(sW[0], sW[1]), fmaxf(sW[2], sW[3]));
    #pragma unroll
    for (int k = 0; k < 4; k++) {
        int i = tid + 256 * k;
        er[(size_t)b * TT + i] = __expf(rowmax[(size_t)b * TT + i] - K);
    }
    if (tid < JJ) {
        float cm = -1e30f;
        #pragma unroll
        for (int tb = 0; tb < 16; tb++) cm = fmaxf(cm, pm[((size_t)b * 16 + tb) * JJ + tid]);
        float cs = 0.f;
        #pragma unroll
        for (int tb = 0; tb < 16; tb++)
            cs += ps[((size_t)b * 16 + tb) * JJ + tid] * __expf(pm[((size_t)b * 16 + tb) * JJ + tid] - cm);
        ec[b * JJ + tid] = __expf(K - cm) / cs;
    }
}

// ---------------------------------------------------------------------------
// K4 (MFMA): tmpT[b,d,j] = sum_t G[t,j]*C[t,d], G = X * er[t] * ec[j]
// (no exp in the hot loop). A = G^T [j][t], B = C^T [d][t]; 128j x 32d tiles.
// ---------------------------------------------------------------------------
__global__ __launch_bounds__(256) void k_tmp(const u16* __restrict__ Xg,
                                             const float* __restrict__ C,
                                             const float* __restrict__ er,
                                             const float* __restrict__ ec,
                                             u16* __restrict__ Tt) {
    const int b  = blockIdx.y;
    const int d0 = blockIdx.x * 32;
    const int tid = threadIdx.x;
    __shared__ __align__(16) u16 sG[128 * 72];    // [j][t] stride 72
    __shared__ __align__(16) u16 sCt[32 * 72];    // [d][t] stride 72
    __shared__ float sEC[128];
    if (tid < 128) sEC[tid] = ec[b * JJ + tid];
    const int lane = tid & 63, wv = tid >> 6;
    const int lr = lane & 15, lg = lane >> 4;
    f32x4 zero4 = {0.f, 0.f, 0.f, 0.f};
    f32x4 acc[2][2];
    acc[0][0] = zero4; acc[0][1] = zero4; acc[1][0] = zero4; acc[1][1] = zero4;

    for (int tt = 0; tt < TT; tt += 64) {
        __syncthreads();
        // stage G^T = X * er * ec (bf16)
        #pragma unroll
        for (int i = 0; i < 4; i++) {
            int c = tid + 256 * i;
            int trow = c >> 4, j0 = (c & 15) * 8;
            int gt = tt + trow;
            float e = er[(size_t)b * TT + gt];
            uint4 xv = *(const uint4*)&Xg[((size_t)b * TT + gt) * JJ + j0];
            const u16* xp = (const u16*)&xv;
            #pragma unroll
            for (int u = 0; u < 8; u++) {
                float g = bf2f(xp[u]) * e * sEC[j0 + u];
                sG[(j0 + u) * 72 + trow] = f2bf(g);
            }
        }
        // stage C^T
        #pragma unroll
        for (int i = 0; i < 2; i++) {
            int c = tid + 256 * i;
            int trow = c >> 3, dcl = (c & 7) * 4;
            float4 cv = *(const float4*)&C[((size_t)b * TT + tt + trow) * DD + d0 + dcl];
            sCt[(dcl + 0) * 72 + trow] = f2bf(cv.x);
            sCt[(dcl + 1) * 72 + trow] = f2bf(cv.y);
            sCt[(dcl + 2) * 72 + trow] = f2bf(cv.z);
            sCt[(dcl + 3) * 72 + trow] = f2bf(cv.w);
        }
        __syncthreads();
        #pragma unroll
        for (int ks = 0; ks < 2; ks++) {
            int kc = ks * 32 + lg * 8;
            s16x8 a0 = *(const s16x8*)&sG[(wv * 32 + lr) * 72 + kc];
            s16x8 a1 = *(const s16x8*)&sG[(wv * 32 + 16 + lr) * 72 + kc];
            s16x8 b0 = *(const s16x8*)&sCt[(lr) * 72 + kc];
            s16x8 b1 = *(const s16x8*)&sCt[(16 + lr) * 72 + kc];
            acc[0][0] = MFMA_BF16(a0, b0, acc[0][0]);
            acc[0][1] = MFMA_BF16(a0, b1, acc[0][1]);
            acc[1][0] = MFMA_BF16(a1, b0, acc[1][0]);
            acc[1][1] = MFMA_BF16(a1, b1, acc[1][1]);
        }
    }
    #pragma unroll
    for (int mr = 0; mr < 2; mr++)
        #pragma unroll
        for (int nr = 0; nr < 2; nr++)
            #pragma unroll
            for (int reg = 0; reg < 4; reg++) {
                int j = wv * 32 + mr * 16 + lg * 4 + reg;
                int d = d0 + nr * 16 + lr;
                Tt[((size_t)b * DD + d) * JJ + j] = f2bf(acc[mr][nr][reg]);
            }
}

// ---------------------------------------------------------------------------
// K5 (MFMA): A = (X·rowrcp)·Q, Bm = (X·rowrcp)·tmp; out = [C, A, C*A, C*Bm].
// ---------------------------------------------------------------------------
__global__ __launch_bounds__(256) void k_out(const u16* __restrict__ Xg,
                                             const u16* __restrict__ Qt,
                                             const u16* __restrict__ Tt,
                                             const float* __restrict__ C,
                                             const float* __restrict__ rowrcp,
                                             float* __restrict__ out) {
    const int b  = blockIdx.y;
    const int tc = blockIdx.x >> 2, dc = blockIdx.x & 3;
    const int t0 = tc * 64, d0 = dc * 64;
    const int tid = threadIdx.x;
    __shared__ __align__(16) u16 sX[64 * 136];
    __shared__ __align__(16) u16 sQ[64 * 136];
    __shared__ __align__(16) u16 sT[64 * 136];
    const size_t xbase = ((size_t)b * TT + t0) * JJ;
    const size_t qbase = ((size_t)b * DD + d0) * JJ;
    #pragma unroll
    for (int i = 0; i < 4; i++) {
        int c = tid + 256 * i;
        int row = c >> 4, col = (c & 15) * 8;
        int lo = row * 136 + col;
        *(uint4*)&sX[lo] = *(const uint4*)&Xg[xbase + (size_t)row * JJ + col];
        *(uint4*)&sQ[lo] = *(const uint4*)&Qt[qbase + (size_t)row * JJ + col];
        *(uint4*)&sT[lo] = *(const uint4*)&Tt[qbase + (size_t)row * JJ + col];
    }
    __syncthreads();
    const int lane = tid & 63, wv = tid >> 6;
    const int wm = wv >> 1, wn = wv & 1;
    const int lr = lane & 15, lg = lane >> 4;
    f32x4 zero4 = {0.f, 0.f, 0.f, 0.f};
    f32x4 accA[2][2], accB[2][2];
    #pragma unroll
    for (int mr = 0; mr < 2; mr++)
        #pragma unroll
        for (int nr = 0; nr < 2; nr++) { accA[mr][nr] = zero4; accB[mr][nr] = zero4; }

    #pragma unroll
    for (int ks = 0; ks < 4; ks++) {
        int kc = ks * 32 + lg * 8;
        s16x8 a0 = *(const s16x8*)&sX[(wm * 32 + lr) * 136 + kc];
        s16x8 a1 = *(const s16x8*)&sX[(wm * 32 + 16 + lr) * 136 + kc];
        s16x8 q0 = *(const s16x8*)&sQ[(wn * 32 + lr) * 136 + kc];
        s16x8 q1 = *(const s16x8*)&sQ[(wn * 32 + 16 + lr) * 136 + kc];
        s16x8 u0 = *(const s16x8*)&sT[(wn * 32 + lr) * 136 + kc];
        s16x8 u1 = *(const s16x8*)&sT[(wn * 32 + 16 + lr) * 136 + kc];
        accA[0][0] = MFMA_BF16(a0, q0, accA[0][0]);
        accA[0][1] = MFMA_BF16(a0, q1, accA[0][1]);
        accA[1][0] = MFMA_BF16(a1, q0, accA[1][0]);
        accA[1][1] = MFMA_BF16(a1, q1, accA[1][1]);
        accB[0][0] = MFMA_BF16(a0, u0, accB[0][0]);
        accB[0][1] = MFMA_BF16(a0, u1, accB[0][1]);
        accB[1][0] = MFMA_BF16(a1, u0, accB[1][0]);
        accB[1][1] = MFMA_BF16(a1, u1, accB[1][1]);
    }

    #pragma unroll
    for (int mr = 0; mr < 2; mr++) {
        #pragma unroll
        for (int reg = 0; reg < 4; reg++) {
            int t = t0 + wm * 32 + mr * 16 + lg * 4 + reg;
            float r = rowrcp[(size_t)b * TT + t];
            const float* Cp = C + ((size_t)b * TT + t) * DD;
            float* op = out + ((size_t)b * TT + t) * (4 * DD);
            #pragma unroll
            for (int nr = 0; nr < 2; nr++) {
                int d = d0 + wn * 32 + nr * 16 + lr;
                float cv = Cp[d];
                float av = accA[mr][nr][reg] * r;
                float bv = accB[mr][nr][reg] * r;
                op[d]          = cv;
                op[DD + d]     = av;
                op[2 * DD + d] = cv * av;
                op[3 * DD + d] = cv * bv;
            }
        }
    }
}

// ---------------------------------------------------------------------------
extern "C" void kernel_launch(void* const* d_in, const int* in_sizes, int n_in,
                              void* d_out, int out_size, void* d_ws, size_t ws_size,
                              hipStream_t stream) {
    const float* C = (const float*)d_in[0];
    const float* Q = (const float*)d_in[1];
    const float* w = (const float*)d_in[2];
    float* out = (float*)d_out;
    float* p = (float*)d_ws;

    u16* Xg  = (u16*)p;     p += (size_t)BB * TT * JJ / 2;   // bf16 X
    u16* Qt  = (u16*)p;     p += (size_t)BB * DD * JJ / 2;   // bf16 Q^T
    u16* Qhi = (u16*)p;     p += (size_t)BB * JJ * DD / 2;   // bf16 Q hi
    u16* Qlo = (u16*)p;     p += (size_t)BB * JJ * DD / 2;   // bf16 Q lo
    u16* Tt  = (u16*)p;     p += (size_t)BB * DD * JJ / 2;   // bf16 tmp^T
    float* ch     = p;      p += BB * TT;
    float* qu     = p;      p += BB * JJ;
    float* rowmax = p;      p += BB * TT;
    float* rowrcp = p;      p += BB * TT;
    float* er     = p;      p += BB * TT;
    float* ec     = p;      p += BB * JJ;
    float* pm     = p;      p += (size_t)BB * 16 * JJ;
    float* ps     = p;      p += (size_t)BB * 16 * JJ;

    const int nrows = BB * TT + BB * JJ;
    k_rowdots<<<dim3((nrows + 3) / 4), dim3(256), 0, stream>>>(C, Q, w, ch, qu);
    k_qtrans <<<dim3(DD / 64, BB), dim3(256), 0, stream>>>(Q, Qt, Qhi, Qlo);
    k_S      <<<dim3(TT / 64, BB), dim3(256), 0, stream>>>(C, Qhi, Qlo, w, ch, qu, Xg, rowmax, rowrcp, pm, ps);
    k_colred <<<dim3(BB), dim3(256), 0, stream>>>(pm, ps, rowmax, er, ec);
    k_tmp    <<<dim3(DD / 32, BB), dim3(256), 0, stream>>>(Xg, C, er, ec, Tt);
    k_out    <<<dim3(16 * 4, BB), dim3(256), 0, stream>>>(Xg, Qt, Tt, C, rowrcp, out);
}